// Round 3
// baseline (405.034 us; speedup 1.0000x reference)
//
#include <hip/hip_runtime.h>

#define BB    8
#define LSEQ  4096
#define DD    4096
#define EE    8
#define RR    16
#define KK    2
#define NSLICE 128
#define LORA_SCALE (1.0f / 16.0f)   // ALPHA / R
#define LN_EPS 1e-5f

typedef float f4 __attribute__((ext_vector_type(4)));

__device__ __forceinline__ float wave_sum(float v) {
#pragma unroll
    for (int off = 32; off > 0; off >>= 1)
        v += __shfl_xor(v, off, 64);
    return v;
}

__device__ __forceinline__ float dot4(f4 a, f4 b) {
    return a.x * b.x + a.y * b.y + a.z * b.z + a.w * b.w;
}

// ---------------------------------------------------------------------------
// Kernel 1: partial column sums of x over a slice of L.
// 1D grid of BB*NSLICE blocks; consecutive blocks stream consecutive 512KB
// chunks. Thread owns 4 float4 columns. Deterministic (no atomics).
// ---------------------------------------------------------------------------
__global__ __launch_bounds__(256) void colsum_kernel(
    const f4* __restrict__ x, f4* __restrict__ partial, int rows_per_slice)
{
    const int tid = threadIdx.x;
    const int bid = blockIdx.x;
    const int b  = bid >> 7;           // / NSLICE
    const int sl = bid & (NSLICE - 1);
    const size_t row0 = (size_t)b * LSEQ + (size_t)sl * rows_per_slice;
    const f4* p = x + row0 * (DD / 4);

    f4 acc[4];
#pragma unroll
    for (int i = 0; i < 4; ++i) acc[i] = (f4)(0.f);

#pragma unroll 2
    for (int l = 0; l < rows_per_slice; ++l) {
        const f4* pr = p + (size_t)l * (DD / 4);
#pragma unroll
        for (int i = 0; i < 4; ++i)
            acc[i] += pr[tid + i * 256];
    }
    f4* dst = partial + ((size_t)sl * BB + b) * (DD / 4);
#pragma unroll
    for (int i = 0; i < 4; ++i) dst[tid + i * 256] = acc[i];
}

// ---------------------------------------------------------------------------
// Kernel 2: router (top-2 softmax) + LoRA delta, one 1024-thread block per b.
// Each thread owns exactly one f4 column (DD/4 == 1024): pooling is a single
// unrolled slice chain; logits/z are single-iteration f4 dots. No hbuf LDS.
// ---------------------------------------------------------------------------
__global__ __launch_bounds__(1024) void router_delta_kernel(
    const f4* __restrict__ partial, int nslice,
    const f4* __restrict__ gate_w, const float* __restrict__ gate_b,
    const f4* __restrict__ A_w, const f4* __restrict__ B_w,
    f4* __restrict__ delta)
{
    __shared__ float redl[EE * 16];
    __shared__ float lgbuf[EE];
    __shared__ float redz[KK * RR * 16];
    __shared__ float zbuf[KK * RR];
    __shared__ int   sel[KK];
    __shared__ float wsel[KK];

    const int b = blockIdx.x;
    const int tid = threadIdx.x;          // == f4 column index, 0..1023
    const int lane = tid & 63;
    const int wid = tid >> 6;             // 0..15

    // h f4 for this thread's column
    f4 acc = (f4)(0.f);
#pragma unroll 8
    for (int sl = 0; sl < nslice; ++sl)
        acc += partial[((size_t)sl * BB + b) * (DD / 4) + tid];
    const f4 h = acc * (1.0f / LSEQ);

    // logits[e] = h . gate_w[e] + gate_b[e]
#pragma unroll
    for (int e = 0; e < EE; ++e) {
        float s = wave_sum(dot4(h, gate_w[e * (DD / 4) + tid]));
        if (lane == 0) redl[e * 16 + wid] = s;
    }
    __syncthreads();
    if (tid < EE) {
        float s = 0.f;
#pragma unroll
        for (int w = 0; w < 16; ++w) s += redl[tid * 16 + w];
        lgbuf[tid] = s + gate_b[tid];
    }
    __syncthreads();
    if (tid == 0) {
        int i0 = 0;
        for (int e = 1; e < EE; ++e) if (lgbuf[e] > lgbuf[i0]) i0 = e;  // ties -> lowest idx
        int i1 = (i0 == 0) ? 1 : 0;
        for (int e = 0; e < EE; ++e) if (e != i0 && lgbuf[e] > lgbuf[i1]) i1 = e;
        float e1 = __expf(lgbuf[i1] - lgbuf[i0]);
        float inv = 1.0f / (1.0f + e1);
        sel[0] = i0; sel[1] = i1;
        wsel[0] = inv; wsel[1] = e1 * inv;
    }
    __syncthreads();

    // z[k][r] = sum_d A_w[sel_k][r][d] * h[d]  — one f4 dot per (k,r)
    const f4* A0 = A_w + (size_t)sel[0] * RR * (DD / 4);
    const f4* A1 = A_w + (size_t)sel[1] * RR * (DD / 4);
#pragma unroll
    for (int r = 0; r < RR; ++r) {
        float s0 = wave_sum(dot4(h, A0[r * (DD / 4) + tid]));
        float s1 = wave_sum(dot4(h, A1[r * (DD / 4) + tid]));
        if (lane == 0) {
            redz[r * 16 + wid] = s0;
            redz[(RR + r) * 16 + wid] = s1;
        }
    }
    __syncthreads();
    if (tid < KK * RR) {
        float s = 0.f;
#pragma unroll
        for (int w = 0; w < 16; ++w) s += redz[tid * 16 + w];
        zbuf[tid] = s;
    }
    __syncthreads();

    // delta[4t+c] = scale * sum_k w_k * sum_r B_w[sel_k][4t+c][r] * z[k][r]
    const float w0 = wsel[0], w1 = wsel[1];
    const f4* B0 = B_w + (size_t)sel[0] * DD * (RR / 4);
    const f4* B1 = B_w + (size_t)sel[1] * DD * (RR / 4);
    f4 o;
#pragma unroll
    for (int c = 0; c < 4; ++c) {
        const int d = tid * 4 + c;
        float s0 = 0.f, s1 = 0.f;
#pragma unroll
        for (int rv = 0; rv < RR / 4; ++rv) {
            f4 b0 = B0[d * (RR / 4) + rv];
            f4 b1 = B1[d * (RR / 4) + rv];
            s0 += b0.x * zbuf[rv * 4] + b0.y * zbuf[rv * 4 + 1]
                + b0.z * zbuf[rv * 4 + 2] + b0.w * zbuf[rv * 4 + 3];
            s1 += b1.x * zbuf[RR + rv * 4] + b1.y * zbuf[RR + rv * 4 + 1]
                + b1.z * zbuf[RR + rv * 4 + 2] + b1.w * zbuf[RR + rv * 4 + 3];
        }
        float v = LORA_SCALE * (w0 * s0 + w1 * s1);
        if (c == 0) o.x = v; else if (c == 1) o.y = v; else if (c == 2) o.z = v; else o.w = v;
    }
    delta[(size_t)b * (DD / 4) + tid] = o;
}

// ---------------------------------------------------------------------------
// Kernel 3: y = LN(x + delta[b]) * gamma + beta. ONE WAVE PER ROW.
// 64 lanes x 16 float4 in registers; butterfly reduce; no LDS, no barriers.
// ---------------------------------------------------------------------------
__global__ __launch_bounds__(256) void resid_ln_kernel(
    const f4* __restrict__ x, const f4* __restrict__ delta,
    const f4* __restrict__ gamma, const f4* __restrict__ beta,
    f4* __restrict__ out)
{
    const int tid = threadIdx.x;
    const int lane = tid & 63, wid = tid >> 6;
    const int row = blockIdx.x * 4 + wid;   // b * LSEQ + l
    const int b = row >> 12;                // LSEQ = 4096
    const f4* xr = x + (size_t)row * (DD / 4);
    const f4* dr = delta + (size_t)b * (DD / 4);

    f4 v[16];
    float sum = 0.f, sq = 0.f;
#pragma unroll
    for (int i = 0; i < 16; ++i) {
        const int idx = lane + i * 64;
        f4 xv = xr[idx];
        f4 dv = dr[idx];
        xv += dv;
        v[i] = xv;
        sum += xv.x + xv.y + xv.z + xv.w;
        sq  += xv.x * xv.x + xv.y * xv.y + xv.z * xv.z + xv.w * xv.w;
    }
    sum = wave_sum(sum);
    sq  = wave_sum(sq);
    const float mean = sum * (1.0f / DD);
    const float var  = sq * (1.0f / DD) - mean * mean;
    const float rstd = rsqrtf(var + LN_EPS);

    f4* orow = out + (size_t)row * (DD / 4);
#pragma unroll
    for (int i = 0; i < 16; ++i) {
        const int idx = lane + i * 64;
        f4 gv = gamma[idx];
        f4 bv = beta[idx];
        f4 xv = v[i];
        f4 o;
        o.x = (xv.x - mean) * rstd * gv.x + bv.x;
        o.y = (xv.y - mean) * rstd * gv.y + bv.y;
        o.z = (xv.z - mean) * rstd * gv.z + bv.z;
        o.w = (xv.w - mean) * rstd * gv.w + bv.w;
        orow[idx] = o;
    }
}

extern "C" void kernel_launch(void* const* d_in, const int* in_sizes, int n_in,
                              void* d_out, int out_size, void* d_ws, size_t ws_size,
                              hipStream_t stream) {
    const float* x      = (const float*)d_in[0];
    const float* gate_w = (const float*)d_in[1];
    const float* gate_b = (const float*)d_in[2];
    const float* A_w    = (const float*)d_in[3];
    const float* B_w    = (const float*)d_in[4];
    const float* gamma  = (const float*)d_in[5];
    const float* beta   = (const float*)d_in[6];
    float* out = (float*)d_out;
    float* ws  = (float*)d_ws;

    float* partial = ws;
    float* delta   = ws + (size_t)NSLICE * BB * DD;

    colsum_kernel<<<BB * NSLICE, 256, 0, stream>>>(
        (const f4*)x, (f4*)partial, LSEQ / NSLICE);

    router_delta_kernel<<<BB, 1024, 0, stream>>>(
        (const f4*)partial, NSLICE, (const f4*)gate_w, gate_b,
        (const f4*)A_w, (const f4*)B_w, (f4*)delta);

    resid_ln_kernel<<<BB * LSEQ / 4, 256, 0, stream>>>(
        (const f4*)x, (const f4*)delta,
        (const f4*)gamma, (const f4*)beta, (f4*)out);
}

// Round 4
// 353.168 us; speedup vs baseline: 1.1469x; 1.1469x over previous
//
#include <hip/hip_runtime.h>

#define BB    8
#define LSEQ  4096
#define DD    4096
#define EE    8
#define RR    16
#define KK    2
#define NSLICE 128
#define LORA_SCALE (1.0f / 16.0f)   // ALPHA / R
#define LN_EPS 1e-5f

typedef float f4 __attribute__((ext_vector_type(4)));

__device__ __forceinline__ float wave_sum(float v) {
#pragma unroll
    for (int off = 32; off > 0; off >>= 1)
        v += __shfl_xor(v, off, 64);
    return v;
}

__device__ __forceinline__ float dot4(f4 a, f4 b) {
    return a.x * b.x + a.y * b.y + a.z * b.z + a.w * b.w;
}

// ---------------------------------------------------------------------------
// Kernel 1: partial column sums of x over a slice of L.
// 1D grid of BB*NSLICE blocks; each block streams 32 consecutive rows
// (512KB contiguous). Nontemporal x loads (stream-once data).
// Deterministic (no atomics): partials land in ws[slice][b][d].
// ---------------------------------------------------------------------------
__global__ __launch_bounds__(256) void colsum_kernel(
    const f4* __restrict__ x, f4* __restrict__ partial, int rows_per_slice)
{
    const int tid = threadIdx.x;
    const int bid = blockIdx.x;
    const int b  = bid >> 7;           // / NSLICE
    const int sl = bid & (NSLICE - 1);
    const size_t row0 = (size_t)b * LSEQ + (size_t)sl * rows_per_slice;
    const f4* p = x + row0 * (DD / 4);

    f4 acc[4];
#pragma unroll
    for (int i = 0; i < 4; ++i) acc[i] = (f4)(0.f);

#pragma unroll 2
    for (int l = 0; l < rows_per_slice; ++l) {
        const f4* pr = p + (size_t)l * (DD / 4);
#pragma unroll
        for (int i = 0; i < 4; ++i)
            acc[i] += __builtin_nontemporal_load(&pr[tid + i * 256]);
    }
    f4* dst = partial + ((size_t)sl * BB + b) * (DD / 4);
#pragma unroll
    for (int i = 0; i < 4; ++i) dst[tid + i * 256] = acc[i];
}

// ---------------------------------------------------------------------------
// Kernel 2: router (top-2 softmax) + LoRA delta, one 1024-thread block per b.
// Each thread owns exactly one f4 column (DD/4 == 1024).
// ---------------------------------------------------------------------------
__global__ __launch_bounds__(1024) void router_delta_kernel(
    const f4* __restrict__ partial, int nslice,
    const f4* __restrict__ gate_w, const float* __restrict__ gate_b,
    const f4* __restrict__ A_w, const f4* __restrict__ B_w,
    f4* __restrict__ delta)
{
    __shared__ float redl[EE * 16];
    __shared__ float lgbuf[EE];
    __shared__ float redz[KK * RR * 16];
    __shared__ float zbuf[KK * RR];
    __shared__ int   sel[KK];
    __shared__ float wsel[KK];

    const int b = blockIdx.x;
    const int tid = threadIdx.x;          // == f4 column index, 0..1023
    const int lane = tid & 63;
    const int wid = tid >> 6;             // 0..15

    // h f4 for this thread's column
    f4 acc = (f4)(0.f);
#pragma unroll 8
    for (int sl = 0; sl < nslice; ++sl)
        acc += partial[((size_t)sl * BB + b) * (DD / 4) + tid];
    const f4 h = acc * (1.0f / LSEQ);

    // logits[e] = h . gate_w[e] + gate_b[e]
#pragma unroll
    for (int e = 0; e < EE; ++e) {
        float s = wave_sum(dot4(h, gate_w[e * (DD / 4) + tid]));
        if (lane == 0) redl[e * 16 + wid] = s;
    }
    __syncthreads();
    if (tid < EE) {
        float s = 0.f;
#pragma unroll
        for (int w = 0; w < 16; ++w) s += redl[tid * 16 + w];
        lgbuf[tid] = s + gate_b[tid];
    }
    __syncthreads();
    if (tid == 0) {
        int i0 = 0;
        for (int e = 1; e < EE; ++e) if (lgbuf[e] > lgbuf[i0]) i0 = e;  // ties -> lowest idx
        int i1 = (i0 == 0) ? 1 : 0;
        for (int e = 0; e < EE; ++e) if (e != i0 && lgbuf[e] > lgbuf[i1]) i1 = e;
        float e1 = __expf(lgbuf[i1] - lgbuf[i0]);
        float inv = 1.0f / (1.0f + e1);
        sel[0] = i0; sel[1] = i1;
        wsel[0] = inv; wsel[1] = e1 * inv;
    }
    __syncthreads();

    // z[k][r] = sum_d A_w[sel_k][r][d] * h[d]  — one f4 dot per (k,r)
    const f4* A0 = A_w + (size_t)sel[0] * RR * (DD / 4);
    const f4* A1 = A_w + (size_t)sel[1] * RR * (DD / 4);
#pragma unroll
    for (int r = 0; r < RR; ++r) {
        float s0 = wave_sum(dot4(h, A0[r * (DD / 4) + tid]));
        float s1 = wave_sum(dot4(h, A1[r * (DD / 4) + tid]));
        if (lane == 0) {
            redz[r * 16 + wid] = s0;
            redz[(RR + r) * 16 + wid] = s1;
        }
    }
    __syncthreads();
    if (tid < KK * RR) {
        float s = 0.f;
#pragma unroll
        for (int w = 0; w < 16; ++w) s += redz[tid * 16 + w];
        zbuf[tid] = s;
    }
    __syncthreads();

    // delta[4t+c] = scale * sum_k w_k * sum_r B_w[sel_k][4t+c][r] * z[k][r]
    const float w0 = wsel[0], w1 = wsel[1];
    const f4* B0 = B_w + (size_t)sel[0] * DD * (RR / 4);
    const f4* B1 = B_w + (size_t)sel[1] * DD * (RR / 4);
    f4 o;
#pragma unroll
    for (int c = 0; c < 4; ++c) {
        const int d = tid * 4 + c;
        float s0 = 0.f, s1 = 0.f;
#pragma unroll
        for (int rv = 0; rv < RR / 4; ++rv) {
            f4 b0 = B0[d * (RR / 4) + rv];
            f4 b1 = B1[d * (RR / 4) + rv];
            s0 += b0.x * zbuf[rv * 4] + b0.y * zbuf[rv * 4 + 1]
                + b0.z * zbuf[rv * 4 + 2] + b0.w * zbuf[rv * 4 + 3];
            s1 += b1.x * zbuf[RR + rv * 4] + b1.y * zbuf[RR + rv * 4 + 1]
                + b1.z * zbuf[RR + rv * 4 + 2] + b1.w * zbuf[RR + rv * 4 + 3];
        }
        float v = LORA_SCALE * (w0 * s0 + w1 * s1);
        if (c == 0) o.x = v; else if (c == 1) o.y = v; else if (c == 2) o.z = v; else o.w = v;
    }
    delta[(size_t)b * (DD / 4) + tid] = o;
}

// ---------------------------------------------------------------------------
// Kernel 3: y = LN(x + delta[b]) * gamma + beta. ONE WAVE PER ROW.
// 64 lanes x 16 float4 in registers; butterfly reduce; no LDS, no barriers.
// Blocks iterate rows in REVERSE so the first K3 blocks read the x-tail that
// K1 touched last (possible L3 residue). nt loads for x, nt stores for out.
// ---------------------------------------------------------------------------
__global__ __launch_bounds__(256) void resid_ln_kernel(
    const f4* __restrict__ x, const f4* __restrict__ delta,
    const f4* __restrict__ gamma, const f4* __restrict__ beta,
    f4* __restrict__ out)
{
    const int tid = threadIdx.x;
    const int lane = tid & 63, wid = tid >> 6;
    const int rgroup = gridDim.x - 1 - blockIdx.x;   // reverse order
    const int row = rgroup * 4 + wid;                // b * LSEQ + l
    const int b = row >> 12;                         // LSEQ = 4096
    const f4* xr = x + (size_t)row * (DD / 4);
    const f4* dr = delta + (size_t)b * (DD / 4);

    f4 v[16];
    float sum = 0.f, sq = 0.f;
#pragma unroll
    for (int i = 0; i < 16; ++i) {
        const int idx = lane + i * 64;
        f4 xv = __builtin_nontemporal_load(&xr[idx]);
        f4 dv = dr[idx];
        xv += dv;
        v[i] = xv;
        sum += xv.x + xv.y + xv.z + xv.w;
        sq  += xv.x * xv.x + xv.y * xv.y + xv.z * xv.z + xv.w * xv.w;
    }
    sum = wave_sum(sum);
    sq  = wave_sum(sq);
    const float mean = sum * (1.0f / DD);
    const float var  = sq * (1.0f / DD) - mean * mean;
    const float rstd = rsqrtf(var + LN_EPS);

    f4* orow = out + (size_t)row * (DD / 4);
#pragma unroll
    for (int i = 0; i < 16; ++i) {
        const int idx = lane + i * 64;
        f4 gv = gamma[idx];
        f4 bv = beta[idx];
        f4 xv = v[i];
        f4 o;
        o.x = (xv.x - mean) * rstd * gv.x + bv.x;
        o.y = (xv.y - mean) * rstd * gv.y + bv.y;
        o.z = (xv.z - mean) * rstd * gv.z + bv.z;
        o.w = (xv.w - mean) * rstd * gv.w + bv.w;
        __builtin_nontemporal_store(o, &orow[idx]);
    }
}

extern "C" void kernel_launch(void* const* d_in, const int* in_sizes, int n_in,
                              void* d_out, int out_size, void* d_ws, size_t ws_size,
                              hipStream_t stream) {
    const float* x      = (const float*)d_in[0];
    const float* gate_w = (const float*)d_in[1];
    const float* gate_b = (const float*)d_in[2];
    const float* A_w    = (const float*)d_in[3];
    const float* B_w    = (const float*)d_in[4];
    const float* gamma  = (const float*)d_in[5];
    const float* beta   = (const float*)d_in[6];
    float* out = (float*)d_out;
    float* ws  = (float*)d_ws;

    float* partial = ws;
    float* delta   = ws + (size_t)NSLICE * BB * DD;

    colsum_kernel<<<BB * NSLICE, 256, 0, stream>>>(
        (const f4*)x, (f4*)partial, LSEQ / NSLICE);

    router_delta_kernel<<<BB, 1024, 0, stream>>>(
        (const f4*)partial, NSLICE, (const f4*)gate_w, gate_b,
        (const f4*)A_w, (const f4*)B_w, (f4*)delta);

    resid_ln_kernel<<<BB * LSEQ / 4, 256, 0, stream>>>(
        (const f4*)x, (const f4*)delta,
        (const f4*)gamma, (const f4*)beta, (f4*)out);
}